// Round 1
// baseline (3056.089 us; speedup 1.0000x reference)
//
#include <hip/hip_runtime.h>
#include <stdint.h>

// WeldRNN: B=64, S=512, H=1024, ReLU Elman RNN, fp32 in/out.
// Persistent cooperative kernel: 4 groups x 16 CUs, 16 batches/group,
// 64 W_hh rows per CU held in registers as bf16 MFMA B-fragments.
// Per step: h broadcast through LLC (system-scope uncached ld/st, double
// buffered), flag-based group barrier, MFMA 16x16x32 bf16, fused epilogue.

#define HIDDEN   1024
#define SEQ      512
#define NGROUPS  4
#define GCUS     16      // CUs (workgroups) per group
#define GBATCH   16      // batches per group
#define ROWS     64      // W_hh rows per CU
#define THREADS  512     // 8 waves

typedef __attribute__((ext_vector_type(4))) float  f32x4;
typedef __attribute__((ext_vector_type(8))) short  short8;

__device__ __forceinline__ unsigned short f2bf(float f) {
    unsigned int u = __float_as_uint(f);
    return (unsigned short)((u + 0x7fffu + ((u >> 16) & 1u)) >> 16);
}

// ws layout: [0..16): flags (4 x int). [256 ...): h_buf per group:
//   group stride = 2 bufs * GBATCH * HIDDEN * 2B = 65536 B.
#define WS_HBUF_OFF 256
#define HBUF_GROUP_STRIDE (2 * GBATCH * HIDDEN)   // in ushorts

__global__ __launch_bounds__(THREADS, 1)
void weld_rnn_kernel(const float* __restrict__ src,
                     const float* __restrict__ W_ih,
                     const float* __restrict__ W_hh,
                     const float* __restrict__ b_ih,
                     const float* __restrict__ b_hh,
                     const float* __restrict__ W_out,
                     const float* __restrict__ b_out,
                     float* __restrict__ out,
                     unsigned char* __restrict__ ws)
{
    const int wg    = blockIdx.x;       // 0..63
    const int group = wg >> 4;          // 0..3
    const int cu    = wg & 15;          // 0..15 within group
    const int row0  = cu * ROWS;        // this CU's W_hh row base
    const int tid   = threadIdx.x;
    const int wv    = tid >> 6;         // wave 0..7 (owns k-eighth)
    const int l     = tid & 63;         // lane

    int* flag = (int*)ws + group;
    unsigned short* hbuf =
        (unsigned short*)(ws + WS_HBUF_OFF) + group * HBUF_GROUP_STRIDE;

    __shared__ f32x4 zpart[8][4][64];   // 32 KB: [wave][tile][lane]

    // ---- init: W_hh rows -> register-resident bf16 B-fragments ----
    // B-frag (16x16x32): lane holds B[k=(l>>4)*8+i][n=l&15]; n = row-in-tile.
    short8 wfrag[4][4];                 // [tile t][chunk cc]; chunk = wv*4+cc
    {
        const int kb = (l >> 4) * 8;
        const int rr = l & 15;
#pragma unroll
        for (int t = 0; t < 4; ++t) {
            const int r = row0 + t * 16 + rr;
#pragma unroll
            for (int cc = 0; cc < 4; ++cc) {
                const int k = (wv * 4 + cc) * 32 + kb;
                const float* p = W_hh + (size_t)r * HIDDEN + k;
                short8 f;
#pragma unroll
                for (int i = 0; i < 8; ++i) f[i] = (short)f2bf(p[i]);
                wfrag[t][cc] = f;
            }
        }
    }

    // ---- epilogue per-lane constants (threads 0..255 own outputs) ----
    // C/D frag: col = l&15 (row within tile), row m = (l>>4)*4+reg = batch.
    float wih0=0,wih1=0,wih2=0,wih3=0,wih4=0,wih5=0, xb=0, wo=0;
    int r_epi = 0;
    if (tid < 256) {
        const int t_ = tid >> 6, le = tid & 63;
        r_epi = row0 + t_ * 16 + (le & 15);
        const float* wp = W_ih + (size_t)r_epi * 6;
        wih0=wp[0]; wih1=wp[1]; wih2=wp[2]; wih3=wp[3]; wih4=wp[4]; wih5=wp[5];
        xb = b_ih[r_epi] + b_hh[r_epi];
        wo = W_out[r_epi];
    }

    // ---- time loop ----
    for (int t = 0; t < SEQ; ++t) {
        f32x4 zepi = {0.f, 0.f, 0.f, 0.f};

        if (t > 0) {
            // wait for all 16 CUs of group to finish step t-1
            if (tid == 0) {
                const int target = GCUS * t;
                while (__hip_atomic_load(flag, __ATOMIC_RELAXED,
                                         __HIP_MEMORY_SCOPE_SYSTEM) < target)
                    __builtin_amdgcn_s_sleep(1);
            }
            __syncthreads();

            const unsigned short* hb =
                hbuf + ((t - 1) & 1) * (GBATCH * HIDDEN);
            const int m  = l & 15;           // A-frag row = local batch
            const int kb = (l >> 4) * 8;

            // prefetch all 4 chunks' A-fragments (system scope, LLC)
            unsigned long long a0[4], a1[4];
#pragma unroll
            for (int cc = 0; cc < 4; ++cc) {
                const int k = (wv * 4 + cc) * 32 + kb;
                const unsigned long long* ap =
                    (const unsigned long long*)(hb + (size_t)m * HIDDEN + k);
                a0[cc] = __hip_atomic_load(ap,     __ATOMIC_RELAXED,
                                           __HIP_MEMORY_SCOPE_SYSTEM);
                a1[cc] = __hip_atomic_load(ap + 1, __ATOMIC_RELAXED,
                                           __HIP_MEMORY_SCOPE_SYSTEM);
            }

            f32x4 acc[4];
#pragma unroll
            for (int t2 = 0; t2 < 4; ++t2) acc[t2] = (f32x4){0.f,0.f,0.f,0.f};
#pragma unroll
            for (int cc = 0; cc < 4; ++cc) {
                union { unsigned long long q[2]; short8 s; } af;
                af.q[0] = a0[cc]; af.q[1] = a1[cc];
#pragma unroll
                for (int t2 = 0; t2 < 4; ++t2)
                    acc[t2] = __builtin_amdgcn_mfma_f32_16x16x32_bf16(
                        af.s, wfrag[t2][cc], acc[t2], 0, 0, 0);
            }
#pragma unroll
            for (int t2 = 0; t2 < 4; ++t2) zpart[wv][t2][l] = acc[t2];
            __syncthreads();

            if (tid < 256) {
                const int t_ = tid >> 6, le = tid & 63;
                f32x4 s = zpart[0][t_][le];
#pragma unroll
                for (int w2 = 1; w2 < 8; ++w2) s += zpart[w2][t_][le];
                zepi = s;
            }
        }

        // ---- epilogue: x-proj + ReLU + h store + out projection ----
        if (tid < 256) {
            const int t_ = tid >> 6, le = tid & 63;
            const int bq = le >> 4;                 // batch quad
            float hn[4];
#pragma unroll
            for (int j = 0; j < 4; ++j) {
                const int b  = bq * 4 + j;          // local batch
                const int bg = group * GBATCH + b;  // global batch
                const float* sp = src + ((size_t)bg * SEQ + t) * 6;
                float x = xb;
                x += sp[0]*wih0; x += sp[1]*wih1; x += sp[2]*wih2;
                x += sp[3]*wih3; x += sp[4]*wih4; x += sp[5]*wih5;
                const float v = zepi[j] + x;
                hn[j] = v > 0.f ? v : 0.f;
            }
            unsigned short* hw = hbuf + (t & 1) * (GBATCH * HIDDEN);
#pragma unroll
            for (int j = 0; j < 4; ++j) {
                const int b = bq * 4 + j;
                __hip_atomic_store(hw + (size_t)b * HIDDEN + r_epi,
                                   f2bf(hn[j]), __ATOMIC_RELAXED,
                                   __HIP_MEMORY_SCOPE_SYSTEM);
            }
            float po0 = hn[0]*wo, po1 = hn[1]*wo, po2 = hn[2]*wo, po3 = hn[3]*wo;
#pragma unroll
            for (int m2 = 1; m2 < 16; m2 <<= 1) {
                po0 += __shfl_xor(po0, m2, 64);
                po1 += __shfl_xor(po1, m2, 64);
                po2 += __shfl_xor(po2, m2, 64);
                po3 += __shfl_xor(po3, m2, 64);
            }
            if ((le & 15) == 0) {
                float po[4] = {po0, po1, po2, po3};
#pragma unroll
                for (int j = 0; j < 4; ++j) {
                    const int bg = group * GBATCH + bq * 4 + j;
                    float add = po[j];
                    if (cu == 0 && t_ == 0) add += b_out[0];
                    atomicAdd(out + (size_t)bg * SEQ + t, add);
                }
            }
        }

        __syncthreads();   // drains vmcnt(0): all h stores visible at LLC
        if (tid == 0)
            __hip_atomic_fetch_add(flag, 1, __ATOMIC_RELEASE,
                                   __HIP_MEMORY_SCOPE_SYSTEM);
    }
}

extern "C" void kernel_launch(void* const* d_in, const int* in_sizes, int n_in,
                              void* d_out, int out_size, void* d_ws, size_t ws_size,
                              hipStream_t stream) {
    (void)in_sizes; (void)n_in; (void)out_size; (void)ws_size;
    const float* src   = (const float*)d_in[0];
    const float* W_ih  = (const float*)d_in[1];
    const float* W_hh  = (const float*)d_in[2];
    const float* b_ih  = (const float*)d_in[3];
    const float* b_hh  = (const float*)d_in[4];
    const float* W_out = (const float*)d_in[5];
    const float* b_out = (const float*)d_in[6];
    float* outp = (float*)d_out;
    unsigned char* wsp = (unsigned char*)d_ws;

    // zero the group flags + zero d_out (it is atomicAdd-accumulated)
    hipMemsetAsync(wsp, 0, 256, stream);
    hipMemsetAsync(outp, 0, 64 * 512 * sizeof(float), stream);

    void* args[] = { (void*)&src, (void*)&W_ih, (void*)&W_hh, (void*)&b_ih,
                     (void*)&b_hh, (void*)&W_out, (void*)&b_out,
                     (void*)&outp, (void*)&wsp };
    hipLaunchCooperativeKernel((void*)weld_rnn_kernel,
                               dim3(NGROUPS * GCUS), dim3(THREADS),
                               args, 0, stream);
}

// Round 12
// 2148.738 us; speedup vs baseline: 1.4223x; 1.4223x over previous
//
#include <hip/hip_runtime.h>
#include <stdint.h>

// WeldRNN: B=64, S=512, H=1024, ReLU Elman RNN, fp32 in/out.
// Round 12 = identical resubmit of the R5 design (seven straight
// GPU-acquisition timeouts; the design has never executed on hardware).
// Audits completed while waiting: staffing/deadlock proof (grid barrier:
// all WGs increment ctr before any exit), fallback rank arithmetic,
// cooperative-launch occupancy validation (1 blk/CU @ 512thr/~200VGPR/
// 64KB LDS -> 256 WGs fit), LDS limits, ws 0xAA-poisoning semantics,
// worst-case analysis (full fallback == R1-speed, still passes).
// Design recap (evidence R1-R4):
//   R1 SYSTEM-scope everywhere: PASSED, 2984 us (h exchange via HBM ~900cy).
//   R2/R3 AGENT-scope cross-XCD: numerically wrong -> AGENT coherence point
//        is the XCD's L2, not device-wide.
//   R4 XCD-local groups requiring >=8 WGs/XCD: deadlock when placement
//        uneven -> container reset.
// Now: 256 WGs cooperative. Each claims a slot on its physical XCD (SYSTEM
// atomics), DIY grid barrier, then all WGs deterministically compute group
// assignment from final claims[]: XCDs with >=8 claimants host local groups
// (AGENT/L2 protocol, ~200cy exchange); remaining groups are formed from
// spare WGs by deterministic rank and run the R1-proven SYSTEM protocol.
// Exactly 8 groups always -> no poll ever waits on an unset flag.

#define HIDDEN   1024
#define SEQ      512
#define NGR      8        // groups
#define GCUS     8        // CUs per group
#define GBATCH   8        // batches per group
#define ROWS     128      // W_hh rows per CU
#define THREADS  512      // 8 waves; wave w owns k-slice w*128
#define LAUNCH_WGS 256

typedef __attribute__((ext_vector_type(4))) float  f32x4;
typedef __attribute__((ext_vector_type(8))) short  short8;
typedef unsigned long long ull;

__device__ __forceinline__ unsigned short f2bf(float f) {
    unsigned int u = __float_as_uint(f);
    return (unsigned short)((u + 0x7fffu + ((u >> 16) & 1u)) >> 16);
}

// ws layout (bytes), [0,4096) zeroed by host each launch:
//   [0, 1024)    : flags: group g at g*128, ints [0..8) per-CU step counts
//   [2048, 2080) : claims[8] (per-XCD slot counters)
//   [2304)       : ctr (DIY grid barrier)
//   [4096, ...)  : h buffers: per group 2 x 16(row pad) x 1024 bf16 = 64KB
#define WS_CLAIMS_OFF 2048
#define WS_CTR_OFF    2304
#define WS_HBUF_OFF   4096
#define HBUF_GROUP_STRIDE (2 * 16 * HIDDEN)   // ushorts

template<int LOCAL>
__device__ void rnn_body(const float* __restrict__ src,
                         const float* __restrict__ W_ih,
                         const float* __restrict__ W_hh,
                         const float* __restrict__ b_ih,
                         const float* __restrict__ b_hh,
                         const float* __restrict__ W_out,
                         const float* __restrict__ b_out,
                         float* __restrict__ out,
                         int* flags, unsigned short* hbuf,
                         int g, int mem, int tid,
                         f32x4 (*zpart)[8][64], float (*po_lds)[GBATCH])
{
    constexpr int SC = LOCAL ? __HIP_MEMORY_SCOPE_AGENT
                             : __HIP_MEMORY_SCOPE_SYSTEM;
    const int w    = tid >> 6;          // wave: k-slice w*128, out tile w
    const int l    = tid & 63;
    const int row0 = mem * ROWS;
    const int kb   = (l >> 4) * 8;

    // ---- W_hh rows -> register bf16 B-fragments ----
    // B-frag 16x16x32: lane holds B[k=(l>>4)*8+i][n=l&15]; n = row-in-tile.
    short8 wfrag[8][4];                 // [tile][chunk]; k = w*128+c*32+kb
#pragma unroll
    for (int t2 = 0; t2 < 8; ++t2) {
        const int r = row0 + t2 * 16 + (l & 15);
#pragma unroll
        for (int c = 0; c < 4; ++c) {
            const float* p = W_hh + (size_t)r * HIDDEN + w * 128 + c * 32 + kb;
            const f32x4 p0 = *(const f32x4*)(p);
            const f32x4 p1 = *(const f32x4*)(p + 4);
            short8 f;
            f[0] = (short)f2bf(p0[0]); f[1] = (short)f2bf(p0[1]);
            f[2] = (short)f2bf(p0[2]); f[3] = (short)f2bf(p0[3]);
            f[4] = (short)f2bf(p1[0]); f[5] = (short)f2bf(p1[1]);
            f[6] = (short)f2bf(p1[2]); f[7] = (short)f2bf(p1[3]);
            wfrag[t2][c] = f;
        }
    }

    // ---- epilogue per-lane constants ----
    // C/D frag: col = l&15 = row-in-tile (this wave's tile = w); row = batch.
    const int  bq    = l >> 4;
    const bool valid = (bq < 2);        // batches 0..7 only (M=16 half-used)
    const int  r_epi = row0 + w * 16 + (l & 15);
    const float* wp  = W_ih + (size_t)r_epi * 6;
    const float wih0 = wp[0], wih1 = wp[1], wih2 = wp[2],
                wih3 = wp[3], wih4 = wp[4], wih5 = wp[5];
    const float xb = b_ih[r_epi] + b_hh[r_epi];
    const float wo = W_out[r_epi];
    const float bo = b_out[0];

    for (int t = 0; t < SEQ; ++t) {
        // ---- x-projection (plain cached loads; hides under the poll) ----
        float xv[4] = {0.f, 0.f, 0.f, 0.f};
        if (valid) {
#pragma unroll
            for (int j = 0; j < 4; ++j) {
                const int bg = g * GBATCH + bq * 4 + j;
                const float* sp = src + ((size_t)bg * SEQ + t) * 6;
                float x = xb;
                x += sp[0]*wih0; x += sp[1]*wih1; x += sp[2]*wih2;
                x += sp[3]*wih3; x += sp[4]*wih4; x += sp[5]*wih5;
                xv[j] = x;
            }
        }

        f32x4 zepi = {0.f, 0.f, 0.f, 0.f};
        if (t > 0) {
            // poll: all 8 group CUs done with step t-1 (also WAR-safe)
            {
                const int* fp = flags + (l & 7);
                int f;
                do {
                    f = __hip_atomic_load(fp, __ATOMIC_RELAXED, SC);
                    if (!LOCAL && !__all(f >= t)) __builtin_amdgcn_s_sleep(1);
                } while (!__all(f >= t));
                asm volatile("" ::: "memory");   // no hoisting h loads above
            }

            // A-fragments: h(t-1) row m=l&15, this wave's k-slice
            const unsigned short* hb = hbuf + ((t - 1) & 1) * (16 * HIDDEN);
            const unsigned short* ap =
                hb + (size_t)(l & 15) * HIDDEN + w * 128 + kb;
            ull q[8];
#pragma unroll
            for (int c = 0; c < 4; ++c) {
                const ull* p = (const ull*)(ap + c * 32);
                q[2*c]   = __hip_atomic_load(p,     __ATOMIC_RELAXED, SC);
                q[2*c+1] = __hip_atomic_load(p + 1, __ATOMIC_RELAXED, SC);
            }

            f32x4 acc[8];
#pragma unroll
            for (int t2 = 0; t2 < 8; ++t2) acc[t2] = (f32x4){0.f,0.f,0.f,0.f};
#pragma unroll
            for (int c = 0; c < 4; ++c) {
                union { ull u[2]; short8 s; } af;
                af.u[0] = q[2*c]; af.u[1] = q[2*c+1];
#pragma unroll
                for (int t2 = 0; t2 < 8; ++t2)
                    acc[t2] = __builtin_amdgcn_mfma_f32_16x16x32_bf16(
                        af.s, wfrag[t2][c], acc[t2], 0, 0, 0);
            }
#pragma unroll
            for (int t2 = 0; t2 < 8; ++t2) zpart[w][t2][l] = acc[t2];
            __syncthreads();            // barrier B
            zepi = zpart[0][w][l];
#pragma unroll
            for (int w2 = 1; w2 < 8; ++w2) zepi += zpart[w2][w][l];
        }

        // ---- epilogue: relu + h store ----
        float hn[4];
#pragma unroll
        for (int j = 0; j < 4; ++j) {
            const float v = zepi[j] + xv[j];
            hn[j] = v > 0.f ? v : 0.f;
        }
        if (valid) {
            unsigned short* hw = hbuf + (t & 1) * (16 * HIDDEN);
#pragma unroll
            for (int j = 0; j < 4; ++j) {
                unsigned short* dst = hw + (size_t)(bq*4 + j) * HIDDEN + r_epi;
                if (LOCAL) *dst = f2bf(hn[j]);   // plain write-through to L2
                else __hip_atomic_store(dst, f2bf(hn[j]),
                                        __ATOMIC_RELAXED, SC);
            }
        }

        // out-projection partial over this wave's 16 rows
        float po0 = hn[0]*wo, po1 = hn[1]*wo, po2 = hn[2]*wo, po3 = hn[3]*wo;
#pragma unroll
        for (int m2 = 1; m2 < 16; m2 <<= 1) {
            po0 += __shfl_xor(po0, m2, 64);
            po1 += __shfl_xor(po1, m2, 64);
            po2 += __shfl_xor(po2, m2, 64);
            po3 += __shfl_xor(po3, m2, 64);
        }
        if (valid && (l & 15) == 0) {
            po_lds[w][bq*4+0] = po0; po_lds[w][bq*4+1] = po1;
            po_lds[w][bq*4+2] = po2; po_lds[w][bq*4+3] = po3;
        }

        __syncthreads();                // barrier A: all waves' h stores acked
        if (tid == 0)
            __hip_atomic_store(&flags[mem], t + 1, __ATOMIC_RELEASE, SC);

        // off-critical-path: out partial (device atomic, R1-proven)
        if (tid < GBATCH) {
            float s = 0.f;
#pragma unroll
            for (int w2 = 0; w2 < 8; ++w2) s += po_lds[w2][tid];
            if (mem == 0) s += bo;
            atomicAdd(out + (size_t)(g * GBATCH + tid) * SEQ + t, s);
        }
    }
}

__global__ __launch_bounds__(THREADS, 2)
void weld_rnn_kernel(const float* __restrict__ src,
                     const float* __restrict__ W_ih,
                     const float* __restrict__ W_hh,
                     const float* __restrict__ b_ih,
                     const float* __restrict__ b_hh,
                     const float* __restrict__ W_out,
                     const float* __restrict__ b_out,
                     float* __restrict__ out,
                     unsigned char* __restrict__ ws)
{
    __shared__ f32x4 zpart[8][8][64];   // 64KB
    __shared__ float po_lds[8][GBATCH];
    __shared__ int   sh[3];
    const int tid = threadIdx.x;

    if (tid == 0) {
        int xcc;
        asm volatile("s_getreg_b32 %0, hwreg(HW_REG_XCC_ID, 0, 32)"
                     : "=s"(xcc));
        xcc &= 7;
        int* claims = (int*)(ws + WS_CLAIMS_OFF);
        int* ctr    = (int*)(ws + WS_CTR_OFF);
        const int slot = __hip_atomic_fetch_add(
            &claims[xcc], 1, __ATOMIC_RELAXED, __HIP_MEMORY_SCOPE_SYSTEM);
        __hip_atomic_fetch_add(ctr, 1, __ATOMIC_RELEASE,
                               __HIP_MEMORY_SCOPE_SYSTEM);
        while (__hip_atomic_load(ctr, __ATOMIC_ACQUIRE,
                                 __HIP_MEMORY_SCOPE_SYSTEM) < LAUNCH_WGS)
            __builtin_amdgcn_s_sleep(8);
        int cl[8];
#pragma unroll
        for (int x = 0; x < 8; ++x)
            cl[x] = __hip_atomic_load(&claims[x], __ATOMIC_RELAXED,
                                      __HIP_MEMORY_SCOPE_SYSTEM);
        // XCDs with >=8 claimants host local groups, in XCD-index order.
        int L = 0, lgi = -1;
#pragma unroll
        for (int x = 0; x < 8; ++x)
            if (cl[x] >= 8) { if (x == xcc) lgi = L; ++L; }
        const bool hostedMine = (cl[xcc] >= 8);
        int g = -1, mem = 0, loc = 0;
        if (hostedMine && slot < 8) { g = lgi; mem = slot; loc = 1; }
        else if (L < 8) {
            // deterministic spare rank -> fallback (SYSTEM-scope) groups
            int r = 0;
            for (int x = 0; x < xcc; ++x)
                r += (cl[x] >= 8) ? (cl[x] - 8) : cl[x];
            r += slot - (hostedMine ? 8 : 0);
            if (r < 8 * (8 - L)) { g = L + (r >> 3); mem = r & 7; loc = 0; }
        }
        sh[0] = g; sh[1] = mem; sh[2] = loc;
    }
    __syncthreads();
    const int g = sh[0], mem = sh[1], loc = sh[2];
    if (g < 0) return;                  // parked (WG-uniform)

    int* flags = (int*)(ws + (size_t)g * 128);
    unsigned short* hbuf = (unsigned short*)(ws + WS_HBUF_OFF)
                         + (size_t)g * HBUF_GROUP_STRIDE;

    if (loc) rnn_body<1>(src, W_ih, W_hh, b_ih, b_hh, W_out, b_out, out,
                         flags, hbuf, g, mem, tid, zpart, po_lds);
    else     rnn_body<0>(src, W_ih, W_hh, b_ih, b_hh, W_out, b_out, out,
                         flags, hbuf, g, mem, tid, zpart, po_lds);
}

extern "C" void kernel_launch(void* const* d_in, const int* in_sizes, int n_in,
                              void* d_out, int out_size, void* d_ws, size_t ws_size,
                              hipStream_t stream) {
    (void)in_sizes; (void)n_in; (void)out_size; (void)ws_size;
    const float* src   = (const float*)d_in[0];
    const float* W_ih  = (const float*)d_in[1];
    const float* W_hh  = (const float*)d_in[2];
    const float* b_ih  = (const float*)d_in[3];
    const float* b_hh  = (const float*)d_in[4];
    const float* W_out = (const float*)d_in[5];
    const float* b_out = (const float*)d_in[6];
    float* outp = (float*)d_out;
    unsigned char* wsp = (unsigned char*)d_ws;

    hipMemsetAsync(wsp, 0, 4096, stream);                       // flags+claims
    hipMemsetAsync(outp, 0, 64 * 512 * sizeof(float), stream);  // atomic acc

    void* args[] = { (void*)&src, (void*)&W_ih, (void*)&W_hh, (void*)&b_ih,
                     (void*)&b_hh, (void*)&W_out, (void*)&b_out,
                     (void*)&outp, (void*)&wsp };
    hipLaunchCooperativeKernel((void*)weld_rnn_kernel,
                               dim3(LAUNCH_WGS), dim3(THREADS),
                               args, 0, stream);
}